// Round 5
// baseline (275.652 us; speedup 1.0000x reference)
//
#include <hip/hip_runtime.h>
#include <math.h>

#define BB 16
#define TT 2048
#define CC 1024
#define HH 64
#define MTOT (BB*TT)

typedef _Float16 f16;
typedef _Float16 f16x8 __attribute__((ext_vector_type(8)));
typedef float f32x4 __attribute__((ext_vector_type(4)));

// ws layout (f16 element offsets):
//   Wt [192][1024]   n-major transposed weights (q|k|v)
//   q  [32768][64]   row-major, pre-scaled by 1/8
//   k  [32768][64]   row-major
//   vT [64][32768]   h-major transposed v
#define WT_OFF 0
#define Q_OFF  196608
#define K_OFF  (Q_OFF + (size_t)MTOT*HH)
#define VT_OFF (K_OFF + (size_t)MTOT*HH)

__device__ __forceinline__ void async16(const void* g, void* l) {
    __builtin_amdgcn_global_load_lds(
        (const __attribute__((address_space(1))) unsigned int*)g,
        (__attribute__((address_space(3))) unsigned int*)l, 16, 0, 0);
}

__device__ __forceinline__ f16x8 cvt8(float4 u, float4 v) {
    f16x8 r;
    r[0] = (f16)u.x; r[1] = (f16)u.y; r[2] = (f16)u.z; r[3] = (f16)u.w;
    r[4] = (f16)v.x; r[5] = (f16)v.y; r[6] = (f16)v.z; r[7] = (f16)v.w;
    return r;
}

// ---------------- Kernel 0: W transpose + convert ----------------
__global__ __launch_bounds__(256) void prep_kernel(
    const float* __restrict__ Wq, const float* __restrict__ Wk,
    const float* __restrict__ Wv, f16* __restrict__ ws)
{
    int e = blockIdx.x * 256 + threadIdx.x;      // 196608 elems
    int ng = e >> 10, k = e & 1023;
    int which = ng >> 6, n = ng & 63;
    const float* W = (which == 0) ? Wq : (which == 1) ? Wk : Wv;
    ws[WT_OFF + e] = (f16)W[k * HH + n];
}

// ---------------- Kernel 1: QKV projection ----------------
// BM=64, N=192, BK=64, 512 blocks x 4 waves. x -> registers (prefetched one
// K-iter ahead, outside barriers -> continuous HBM stream). W -> LDS via
// global_load_lds, double-buffered, ONE barrier/iter. Wave w: n-tiles
// {3w..3w+2}, all 4 m-tiles.
__global__ __launch_bounds__(256, 2) void qkv_kernel(
    const float* __restrict__ x,
    const float* __restrict__ bq, const float* __restrict__ bk,
    const float* __restrict__ bv, f16* __restrict__ ws)
{
    __shared__ __align__(16) f16 Ws[2][192 * 64];   // 48 KB dbuf, XOR-swizzled
    __shared__ __align__(16) f16 Vt[64][72];        //  9 KB epilogue transpose

    const f16* wt = ws + WT_OFF;
    const int tid  = threadIdx.x;
    const int lane = tid & 63, w = tid >> 6;
    const int c = lane & 15, g = lane >> 4;
    const int m0 = blockIdx.x * 64;

    f32x4 acc[4][3];
    #pragma unroll
    for (int mt = 0; mt < 4; ++mt)
        #pragma unroll
        for (int j = 0; j < 3; ++j) acc[mt][j] = (f32x4){0.f, 0.f, 0.f, 0.f};

    // stage W(it) into Ws[it&1]: 1536 granules, 6 calls/wave
    #define STAGE_W(it) do {                                             \
        int buf = (it) & 1;                                              \
        _Pragma("unroll")                                                \
        for (int i = 0; i < 6; ++i) {                                    \
            int G0 = (w * 6 + i) * 64;                                   \
            int G = G0 + lane;                                           \
            int r = G >> 3, q = G & 7;                                   \
            async16(wt + (size_t)r * CC + (it) * 64 + ((q ^ (r & 7)) << 3), \
                    &Ws[buf][G0 * 8]);                                   \
        }                                                                \
    } while (0)

    // x A-operands: lane(c,g), m-tile mt, half h -> row m0+mt*16+c,
    // cols k0 + h*32 + g*8 (two float4)
    float4 xa[4][2][2], xb[4][2][2];
    #define LOAD_X(dst, k0) do {                                         \
        _Pragma("unroll")                                                \
        for (int mt = 0; mt < 4; ++mt) {                                 \
            const float* row = x + (size_t)(m0 + mt * 16 + c) * CC + (k0) + g * 8; \
            _Pragma("unroll")                                            \
            for (int h = 0; h < 2; ++h) {                                \
                dst[mt][h][0] = *(const float4*)(row + h * 32);          \
                dst[mt][h][1] = *(const float4*)(row + h * 32 + 4);      \
            }                                                            \
        }                                                                \
    } while (0)

    STAGE_W(0);
    LOAD_X(xa, 0);

    for (int it = 0; it < 16; ++it) {
        __syncthreads();   // Ws[it&1] ready; prev readers done; xa drained
        if (it < 15) {
            STAGE_W(it + 1);
            LOAD_X(xb, (it + 1) * 64);
        }
        const f16* wb = Ws[it & 1];
        f16x8 af[4];
        #pragma unroll
        for (int h = 0; h < 2; ++h) {
            #pragma unroll
            for (int mt = 0; mt < 4; ++mt)
                af[mt] = cvt8(xa[mt][h][0], xa[mt][h][1]);
            #pragma unroll
            for (int j = 0; j < 3; ++j) {
                int r = (3 * w + j) * 16 + c;
                f16x8 bf = *(const f16x8*)(wb + r * 64 + (((h * 4 + g) ^ (c & 7)) << 3));
                #pragma unroll
                for (int mt = 0; mt < 4; ++mt)
                    acc[mt][j] = __builtin_amdgcn_mfma_f32_16x16x32_f16(
                        af[mt], bf, acc[mt][j], 0, 0, 0);
            }
        }
        #pragma unroll
        for (int mt = 0; mt < 4; ++mt)
            #pragma unroll
            for (int h = 0; h < 2; ++h) {
                xa[mt][h][0] = xb[mt][h][0];
                xa[mt][h][1] = xb[mt][h][1];
            }
    }

    // epilogue: C/D row = 4g+r (in 16-tile), col = nt*16+c
    #pragma unroll
    for (int j = 0; j < 3; ++j) {
        int nt = 3 * w + j;
        int plane = nt >> 2;             // 0=q 1=k 2=v
        int h = (nt & 3) * 16 + c;
        if (plane == 0) {
            float bias = bq[h];
            #pragma unroll
            for (int mt = 0; mt < 4; ++mt)
                #pragma unroll
                for (int r = 0; r < 4; ++r) {
                    int m = m0 + mt * 16 + 4 * g + r;
                    ws[Q_OFF + (size_t)m * HH + h] =
                        (f16)((acc[mt][j][r] + bias) * 0.125f);
                }
        } else if (plane == 1) {
            float bias = bk[h];
            #pragma unroll
            for (int mt = 0; mt < 4; ++mt)
                #pragma unroll
                for (int r = 0; r < 4; ++r) {
                    int m = m0 + mt * 16 + 4 * g + r;
                    ws[K_OFF + (size_t)m * HH + h] = (f16)(acc[mt][j][r] + bias);
                }
        } else {
            float bias = bv[h];
            #pragma unroll
            for (int mt = 0; mt < 4; ++mt)
                #pragma unroll
                for (int r = 0; r < 4; ++r)
                    Vt[h][mt * 16 + 4 * g + r] = (f16)(acc[mt][j][r] + bias);
        }
    }
    __syncthreads();
    {   // coalesced vT write
        int h = tid >> 2, seg = tid & 3;
        f16* dst = ws + VT_OFF + (size_t)h * MTOT + m0 + seg * 16;
        *(f16x8*)dst       = *(f16x8*)&Vt[h][seg * 16];
        *(f16x8*)(dst + 8) = *(f16x8*)&Vt[h][seg * 16 + 8];
    }
    #undef STAGE_W
    #undef LOAD_X
}

// ---------------- Kernel 2: causal flash attention ----------------
// 512 blocks x 4 waves; wave w owns q-rows [16w,16w+16). K/V staged 128 s-rows
// per stage, double-buffered, ONE barrier/stage (next-stage loads issue before
// compute -> L2 latency overlapped). Q fragments direct global->reg. Exp-only
// softmax; l via constant ones-column B fragment.
__global__ __launch_bounds__(256, 2) void attn_kernel(
    const f16* __restrict__ ws, float* __restrict__ out)
{
    const f16* qp = ws + Q_OFF;
    const f16* kp = ws + K_OFF;
    const f16* vt = ws + VT_OFF;

    __shared__ __align__(16) f16 Ks[2][128 * 64];   // 32 KB, XOR-swizzled
    __shared__ __align__(16) f16 Vs[2][64 * 128];   // 32 KB, XOR-swizzled
    __shared__ __align__(16) f16 Ps[4][16][72];     // wave-private P round-trip

    const int tid  = threadIdx.x;
    const int lane = tid & 63, w = tid >> 6;
    const int c = lane & 15, g = lane >> 4;

    // swizzle: XCD r8 gets batches 2r8,2r8+1; blocks i,i+256 complementary
    const int id = blockIdx.x;
    const int r8 = id & 7, j = id >> 3;
    const int half = j >> 5, qr = j & 31;
    const int b  = 2 * r8 + half;
    const int qi = half ? (31 - qr) : qr;
    const int q0 = qi * 64;
    const size_t rowbase = (size_t)b * TT;

    // Q A-fragments direct from global (held whole kernel)
    f16x8 aq[2];
    {
        const f16* qrow = qp + (rowbase + q0 + w * 16 + c) * HH + g * 8;
        aq[0] = *(const f16x8*)(qrow);
        aq[1] = *(const f16x8*)(qrow + 32);
    }

    f32x4 o[5];   // 4 output n-tiles + ones-column (row-sum l)
    #pragma unroll
    for (int nt = 0; nt < 5; ++nt) o[nt] = (f32x4){0.f, 0.f, 0.f, 0.f};

    f16x8 onesf;
    #pragma unroll
    for (int i = 0; i < 8; ++i) onesf[i] = (c == 0) ? (f16)1.0f : (f16)0.0f;

    // stage 128 K-rows + V cols [sc*128, +128) into buffer sc&1
    #define STAGE_KV(sc) do {                                            \
        int buf = (sc) & 1;                                              \
        _Pragma("unroll")                                                \
        for (int i = 0; i < 4; ++i) {                                    \
            int G0 = (w * 4 + i) * 64;                                   \
            int G = G0 + lane;                                           \
            int rk = G >> 3, qk = G & 7;                                 \
            async16(kp + (rowbase + (sc) * 128 + rk) * HH + ((qk ^ (rk & 7)) << 3), \
                    &Ks[buf][G0 * 8]);                                   \
            int rv = G >> 4, qv = G & 15;                                \
            async16(vt + (size_t)rv * MTOT + rowbase + (sc) * 128 + ((qv ^ (rv & 15)) << 3), \
                    &Vs[buf][G0 * 8]);                                   \
        }                                                                \
    } while (0)

    const int nsc = (qi >> 1) + 1;
    STAGE_KV(0);

    for (int sc = 0; sc < nsc; ++sc) {
        __syncthreads();   // buffer sc&1 ready; prev readers done
        if (sc + 1 < nsc) STAGE_KV(sc + 1);
        const f16* kb = Ks[sc & 1];
        const f16* vb = Vs[sc & 1];

        #pragma unroll
        for (int u = 0; u < 2; ++u) {
            int jt = 2 * sc + u;
            if (jt > qi) break;

            // S = Q K^T : 8 mfma
            f32x4 s[4];
            #pragma unroll
            for (int nt = 0; nt < 4; ++nt) {
                s[nt] = (f32x4){0.f, 0.f, 0.f, 0.f};
                int r = u * 64 + nt * 16 + c;
                f16x8 b0 = *(const f16x8*)(kb + r * 64 + (((g)     ^ (c & 7)) << 3));
                f16x8 b1 = *(const f16x8*)(kb + r * 64 + (((4 + g) ^ (c & 7)) << 3));
                s[nt] = __builtin_amdgcn_mfma_f32_16x16x32_f16(aq[0], b0, s[nt], 0, 0, 0);
                s[nt] = __builtin_amdgcn_mfma_f32_16x16x32_f16(aq[1], b1, s[nt], 0, 0, 0);
            }

            if (jt == qi) {   // diagonal tile: causal mask
                #pragma unroll
                for (int nt = 0; nt < 4; ++nt)
                    #pragma unroll
                    for (int rr = 0; rr < 4; ++rr)
                        if (nt * 16 + c > w * 16 + 4 * g + rr) s[nt][rr] = -INFINITY;
            }

            // P = exp(S) -> wave-private LDS (C/D -> A layout round-trip)
            #pragma unroll
            for (int nt = 0; nt < 4; ++nt)
                #pragma unroll
                for (int rr = 0; rr < 4; ++rr)
                    Ps[w][4 * g + rr][nt * 16 + c] = (f16)__expf(s[nt][rr]);
            f16x8 pa0 = *(f16x8*)&Ps[w][c][g * 8];
            f16x8 pa1 = *(f16x8*)&Ps[w][c][32 + g * 8];

            // O += P V (+ ones column for l): 10 mfma
            #pragma unroll
            for (int nt = 0; nt < 4; ++nt) {
                int r = nt * 16 + c;
                f16x8 v0 = *(const f16x8*)(vb + r * 128 + (((u * 8 + g)     ^ c) << 3));
                f16x8 v1 = *(const f16x8*)(vb + r * 128 + (((u * 8 + 4 + g) ^ c) << 3));
                o[nt] = __builtin_amdgcn_mfma_f32_16x16x32_f16(pa0, v0, o[nt], 0, 0, 0);
                o[nt] = __builtin_amdgcn_mfma_f32_16x16x32_f16(pa1, v1, o[nt], 0, 0, 0);
            }
            o[4] = __builtin_amdgcn_mfma_f32_16x16x32_f16(pa0, onesf, o[4], 0, 0, 0);
            o[4] = __builtin_amdgcn_mfma_f32_16x16x32_f16(pa1, onesf, o[4], 0, 0, 0);
        }
    }
    #undef STAGE_KV

    // epilogue: l at col 0 of each 16-lane group -> broadcast, normalize
    #pragma unroll
    for (int rr = 0; rr < 4; ++rr) {
        float lv = __shfl(o[4][rr], lane & 48);
        float inv = 1.0f / lv;
        int mrow = q0 + w * 16 + 4 * g + rr;
        #pragma unroll
        for (int nt = 0; nt < 4; ++nt)
            out[(rowbase + mrow) * HH + nt * 16 + c] = o[nt][rr] * inv;
    }
}

extern "C" void kernel_launch(void* const* d_in, const int* in_sizes, int n_in,
                              void* d_out, int out_size, void* d_ws, size_t ws_size,
                              hipStream_t stream) {
    const float* x  = (const float*)d_in[0];
    const float* Wq = (const float*)d_in[1];
    const float* bq = (const float*)d_in[2];
    const float* Wk = (const float*)d_in[3];
    const float* bk = (const float*)d_in[4];
    const float* Wv = (const float*)d_in[5];
    const float* bv = (const float*)d_in[6];
    f16*   ws  = (f16*)d_ws;
    float* out = (float*)d_out;

    prep_kernel<<<768, 256, 0, stream>>>(Wq, Wk, Wv, ws);
    qkv_kernel<<<MTOT / 64, 256, 0, stream>>>(x, bq, bk, bv, ws);
    attn_kernel<<<512, 256, 0, stream>>>(ws, out);
}

// Round 6
// 245.463 us; speedup vs baseline: 1.1230x; 1.1230x over previous
//
#include <hip/hip_runtime.h>
#include <math.h>

#define BB 16
#define TT 2048
#define CC 1024
#define HH 64
#define MTOT (BB*TT)

typedef _Float16 f16;
typedef _Float16 f16x4 __attribute__((ext_vector_type(4)));
typedef _Float16 f16x8 __attribute__((ext_vector_type(8)));
typedef float f32x4 __attribute__((ext_vector_type(4)));

// ws layout (f16 element offsets):
//   Wt [192][1024]   n-major transposed weights (q|k|v)
//   q  [32768][64]   row-major, pre-scaled by 1/8
//   k  [32768][64]   row-major
//   vT [64][32768]   h-major transposed v
#define WT_OFF 0
#define Q_OFF  196608
#define K_OFF  (Q_OFF + (size_t)MTOT*HH)
#define VT_OFF (K_OFF + (size_t)MTOT*HH)

__device__ __forceinline__ void async16(const void* g, void* l) {
    __builtin_amdgcn_global_load_lds(
        (const __attribute__((address_space(1))) unsigned int*)g,
        (__attribute__((address_space(3))) unsigned int*)l, 16, 0, 0);
}

__device__ __forceinline__ f16x8 cvt8(float4 u, float4 v) {
    f16x8 r;
    r[0] = (f16)u.x; r[1] = (f16)u.y; r[2] = (f16)u.z; r[3] = (f16)u.w;
    r[4] = (f16)v.x; r[5] = (f16)v.y; r[6] = (f16)v.z; r[7] = (f16)v.w;
    return r;
}

// ---------------- Kernel 0: W transpose + convert ----------------
__global__ __launch_bounds__(256) void prep_kernel(
    const float* __restrict__ Wq, const float* __restrict__ Wk,
    const float* __restrict__ Wv, f16* __restrict__ ws)
{
    int e = blockIdx.x * 256 + threadIdx.x;      // 196608 elems
    int ng = e >> 10, k = e & 1023;
    int which = ng >> 6, n = ng & 63;
    const float* W = (which == 0) ? Wq : (which == 1) ? Wk : Wv;
    ws[WT_OFF + e] = (f16)W[k * HH + n];
}

// ---------------- Kernel 1: QKV projection (R4 structure: full LDS staging) ----------------
// BM=64, N=192, BK=64. 512 blocks x 4 waves, 3 blocks/CU. Wave w: n-tiles
// {3w..3w+2}, all 4 m-tiles. Xs fp32 / Ws f16 staged via global_load_lds
// with XOR granule swizzle (2-way bank aliasing = free).
__global__ __launch_bounds__(256, 3) void qkv_kernel(
    const float* __restrict__ x,
    const float* __restrict__ bq, const float* __restrict__ bk,
    const float* __restrict__ bv, f16* __restrict__ ws)
{
    __shared__ __align__(16) float Xs[64 * 64];   // 16 KB; reused as Vt post-loop
    __shared__ __align__(16) f16   Ws[192 * 64];  // 24 KB
    f16 (*Vt)[72] = (f16 (*)[72])Xs;              // 9 KB alias (after sync)

    const f16* wt = ws + WT_OFF;
    const int tid  = threadIdx.x;
    const int lane = tid & 63, w = tid >> 6;
    const int c = lane & 15, g = lane >> 4;
    const int m0 = blockIdx.x * 64;

    f32x4 acc[4][3];     // [mt][j]
    #pragma unroll
    for (int mt = 0; mt < 4; ++mt)
        #pragma unroll
        for (int j = 0; j < 3; ++j) acc[mt][j] = (f32x4){0.f, 0.f, 0.f, 0.f};

    for (int k0 = 0; k0 < CC; k0 += 64) {
        __syncthreads();   // previous iteration's fragment reads done
        // stage X tile (64x64 fp32, HBM stream first): 4 calls/wave
        #pragma unroll
        for (int i = 0; i < 4; ++i) {
            int G0 = (w * 4 + i) * 64;
            int G = G0 + lane;
            int r = G >> 4, q = G & 15;
            async16(x + (size_t)(m0 + r) * CC + k0 + ((q ^ (r & 15)) << 2),
                    Xs + G0 * 4);
        }
        // stage W tile (192x64 f16, L2-hot): 6 calls/wave
        #pragma unroll
        for (int i = 0; i < 6; ++i) {
            int G0 = (w * 6 + i) * 64;
            int G = G0 + lane;
            int r = G >> 3, q = G & 7;
            async16(wt + (size_t)r * CC + k0 + ((q ^ (r & 7)) << 3),
                    Ws + G0 * 8);
        }
        __syncthreads();   // vmcnt drain: staged data visible

        #pragma unroll
        for (int kk = 0; kk < 2; ++kk) {
            f16x8 bfr[3];
            #pragma unroll
            for (int j = 0; j < 3; ++j) {
                int r = (3 * w + j) * 16 + c;
                int p = (kk * 4 + g) ^ (c & 7);
                bfr[j] = *(const f16x8*)(Ws + r * 64 + p * 8);
            }
            #pragma unroll
            for (int mt = 0; mt < 4; ++mt) {
                int r = mt * 16 + c;
                int q = kk * 8 + 2 * g;
                float4 f0 = *(const float4*)(Xs + r * 64 + (q ^ c) * 4);
                float4 f1 = *(const float4*)(Xs + r * 64 + ((q + 1) ^ c) * 4);
                f16x8 a = cvt8(f0, f1);
                #pragma unroll
                for (int j = 0; j < 3; ++j)
                    acc[mt][j] = __builtin_amdgcn_mfma_f32_16x16x32_f16(
                        a, bfr[j], acc[mt][j], 0, 0, 0);
            }
        }
    }
    __syncthreads();   // all Xs fragment reads done before Vt alias writes

    // epilogue: C/D row = 4g+r (in 16-tile), col = nt*16+c
    #pragma unroll
    for (int j = 0; j < 3; ++j) {
        int nt = 3 * w + j;
        int plane = nt >> 2;             // 0=q 1=k 2=v
        int h = (nt & 3) * 16 + c;
        if (plane == 0) {
            float bias = bq[h];
            #pragma unroll
            for (int mt = 0; mt < 4; ++mt)
                #pragma unroll
                for (int r = 0; r < 4; ++r) {
                    int m = m0 + mt * 16 + 4 * g + r;
                    ws[Q_OFF + (size_t)m * HH + h] =
                        (f16)((acc[mt][j][r] + bias) * 0.125f);
                }
        } else if (plane == 1) {
            float bias = bk[h];
            #pragma unroll
            for (int mt = 0; mt < 4; ++mt)
                #pragma unroll
                for (int r = 0; r < 4; ++r) {
                    int m = m0 + mt * 16 + 4 * g + r;
                    ws[K_OFF + (size_t)m * HH + h] = (f16)(acc[mt][j][r] + bias);
                }
        } else {
            float bias = bv[h];
            #pragma unroll
            for (int mt = 0; mt < 4; ++mt)
                #pragma unroll
                for (int r = 0; r < 4; ++r)
                    Vt[h][mt * 16 + 4 * g + r] = (f16)(acc[mt][j][r] + bias);
        }
    }
    __syncthreads();
    {   // coalesced vT write
        int h = tid >> 2, seg = tid & 3;
        f16* dst = ws + VT_OFF + (size_t)h * MTOT + m0 + seg * 16;
        *(f16x8*)dst       = *(f16x8*)&Vt[h][seg * 16];
        *(f16x8*)(dst + 8) = *(f16x8*)&Vt[h][seg * 16 + 8];
    }
}

// ---------------- Kernel 2: causal flash attention (S^T formulation) ----------------
// 512 blocks x 4 waves; wave w owns q-rows [16w,16w+16). Computes
// S^T = K·Q^T so P packs to LDS with ds_write_b64 (m-major PsT[m][s]) and
// reads back as contiguous B-fragments for O^T = V^T·P^T. l via in-register
// reduction (2 shuffles). K/V dbuf, ONE barrier/tile. Exp-only softmax.
__global__ __launch_bounds__(256, 3) void attn_kernel(
    const f16* __restrict__ ws, float* __restrict__ out)
{
    const f16* qp = ws + Q_OFF;
    const f16* kp = ws + K_OFF;
    const f16* vt = ws + VT_OFF;

    __shared__ __align__(16) f16 Ks[2][64 * 64];    // 16 KB, XOR-swizzled
    __shared__ __align__(16) f16 Vs[2][64 * 64];    // 16 KB, XOR-swizzled
    __shared__ __align__(16) f16 PsT[4][16][68];    // 8.5 KB wave-private P^T

    const int tid  = threadIdx.x;
    const int lane = tid & 63, w = tid >> 6;
    const int c = lane & 15, g = lane >> 4;

    // swizzle: XCD r8 gets batches 2r8,2r8+1; blocks i,i+256 complementary
    const int id = blockIdx.x;
    const int r8 = id & 7, j = id >> 3;
    const int half = j >> 5, qr = j & 31;
    const int b  = 2 * r8 + half;
    const int qi = half ? (31 - qr) : qr;
    const int q0 = qi * 64;
    const size_t rowbase = (size_t)b * TT;

    // Q B-fragments (held whole kernel): B[k=h][n=q-row]
    f16x8 bq_[2];
    {
        const f16* qrow = qp + (rowbase + q0 + w * 16 + c) * HH + g * 8;
        bq_[0] = *(const f16x8*)(qrow);
        bq_[1] = *(const f16x8*)(qrow + 32);
    }

    f32x4 o[4];   // O^T h-tiles (C layout: row=h=4g+r, col=m=c)
    #pragma unroll
    for (int ht = 0; ht < 4; ++ht) o[ht] = (f32x4){0.f, 0.f, 0.f, 0.f};
    float l_acc = 0.f;

    // stage K rows + V^T rows [st*64, +64) into buffer st&1: 2+2 calls/wave
    #define STAGE_KV(st) do {                                              \
        int buf = (st) & 1;                                                \
        _Pragma("unroll")                                                  \
        for (int i = 0; i < 2; ++i) {                                      \
            int G0 = (w * 2 + i) * 64;                                     \
            int G = G0 + lane;                                             \
            int r = G >> 3, q = G & 7;                                     \
            int sw = (q ^ (r & 7)) << 3;                                   \
            async16(kp + (rowbase + (st) * 64 + r) * HH + sw, &Ks[buf][G0 * 8]); \
            async16(vt + (size_t)r * MTOT + rowbase + (st) * 64 + sw, &Vs[buf][G0 * 8]); \
        }                                                                  \
    } while (0)

    STAGE_KV(0);

    for (int st = 0; st <= qi; ++st) {
        __syncthreads();   // buffer st&1 staged; prev readers of buf^1 done
        if (st < qi) STAGE_KV(st + 1);
        const f16* kb = Ks[st & 1];
        const f16* vb = Vs[st & 1];
        const int tmax = (st == qi) ? w : 3;   // skip fully-masked diag subtiles
        const bool diag = (st == qi);

        // S^T subtiles: A = K rows, B = Q rows; exp; pack to PsT[m][s]
        float lp = 0.f;
        #pragma unroll
        for (int t = 0; t < 4; ++t) {
            f16x4 pv;
            if (t <= tmax) {
                int r = t * 16 + c;
                f16x8 a0 = *(const f16x8*)(kb + r * 64 + (((g)     ^ (c & 7)) << 3));
                f16x8 a1 = *(const f16x8*)(kb + r * 64 + (((4 + g) ^ (c & 7)) << 3));
                f32x4 s = (f32x4){0.f, 0.f, 0.f, 0.f};
                s = __builtin_amdgcn_mfma_f32_16x16x32_f16(a0, bq_[0], s, 0, 0, 0);
                s = __builtin_amdgcn_mfma_f32_16x16x32_f16(a1, bq_[1], s, 0, 0, 0);
                #pragma unroll
                for (int rr = 0; rr < 4; ++rr) {
                    // mask on the t==w diagonal subtile: s_local 4g+rr > c
                    float p = (diag && t == w && (4 * g + rr > c))
                                ? 0.f : __expf(s[rr]);
                    lp += p;
                    pv[rr] = (f16)p;
                }
            } else {
                pv = (f16x4){(f16)0.f, (f16)0.f, (f16)0.f, (f16)0.f};
            }
            *(f16x4*)&PsT[w][c][t * 16 + 4 * g] = pv;   // one ds_write_b64
        }
        // l: reduce the 4 g-groups holding col c
        lp += __shfl_xor(lp, 16);
        lp += __shfl_xor(lp, 32);
        l_acc += lp;

        // O^T += V^T · P^T : B-frags contiguous from PsT (in-wave RAW, ordered)
        f16x8 pb0 = *(const f16x8*)&PsT[w][c][g * 8];
        f16x8 pb1 = *(const f16x8*)&PsT[w][c][32 + g * 8];
        #pragma unroll
        for (int ht = 0; ht < 4; ++ht) {
            int r = ht * 16 + c;
            f16x8 va0 = *(const f16x8*)(vb + r * 64 + (((g)     ^ (c & 7)) << 3));
            f16x8 va1 = *(const f16x8*)(vb + r * 64 + (((4 + g) ^ (c & 7)) << 3));
            o[ht] = __builtin_amdgcn_mfma_f32_16x16x32_f16(va0, pb0, o[ht], 0, 0, 0);
            o[ht] = __builtin_amdgcn_mfma_f32_16x16x32_f16(va1, pb1, o[ht], 0, 0, 0);
        }
    }
    #undef STAGE_KV

    // epilogue: lane owns q-row q0+16w+c, cols 16ht+4g..+3 -> float4 stores
    float inv = 1.0f / l_acc;
    float* orow = out + (rowbase + q0 + w * 16 + c) * HH;
    #pragma unroll
    for (int ht = 0; ht < 4; ++ht) {
        float4 v;
        v.x = o[ht][0] * inv; v.y = o[ht][1] * inv;
        v.z = o[ht][2] * inv; v.w = o[ht][3] * inv;
        *(float4*)(orow + ht * 16 + 4 * g) = v;
    }
}

extern "C" void kernel_launch(void* const* d_in, const int* in_sizes, int n_in,
                              void* d_out, int out_size, void* d_ws, size_t ws_size,
                              hipStream_t stream) {
    const float* x  = (const float*)d_in[0];
    const float* Wq = (const float*)d_in[1];
    const float* bq = (const float*)d_in[2];
    const float* Wk = (const float*)d_in[3];
    const float* bk = (const float*)d_in[4];
    const float* Wv = (const float*)d_in[5];
    const float* bv = (const float*)d_in[6];
    f16*   ws  = (f16*)d_ws;
    float* out = (float*)d_out;

    prep_kernel<<<768, 256, 0, stream>>>(Wq, Wk, Wv, ws);
    qkv_kernel<<<MTOT / 64, 256, 0, stream>>>(x, bq, bk, bv, ws);
    attn_kernel<<<512, 256, 0, stream>>>(ws, out);
}